// Round 5
// baseline (283.658 us; speedup 1.0000x reference)
//
#include <hip/hip_runtime.h>
#include <hip/hip_bf16.h>

#define N   20000
#define E   320000
#define H   64
#define EA  9
#define EPS 1e-5f

#define SVB 136   // LDS row stride in ushorts (272 B, 17 granules -> conflict-friendly)

typedef short s16x8 __attribute__((ext_vector_type(8)));
typedef float f32x4 __attribute__((ext_vector_type(4)));

// ws offsets (u32 units)
#define OFF_DEG    0
#define OFF_CNT1   20000
#define OFF_ATTR   40000       // N*EA
#define OFF_ROWPTR 220000      // N+1 (+pad)
#define OFF_EPOS   240016      // E
#define OFF_PK2    560016      // E int2
#define OFF_HB     1200016     // N*H bf16
#define OFF_AGG    1840016     // N*H f32
#define OFF_W1CHI  3120016     // 3*128*128 ushort = 24576 u32
#define OFF_W1CLO  3144592
#define OFF_W2CHI  3169168     // 3*128*64 ushort = 12288 u32
#define OFF_W2CLO  3181456
// end 3193744 u32 = 12.77 MB

static __device__ __forceinline__ ushort f2bf(float f) {
    union { float f; unsigned u; } v; v.f = f;
    unsigned r = (v.u + 0x7fffu + ((v.u >> 16) & 1u)) >> 16;
    return (ushort)r;
}
static __device__ __forceinline__ float bf2f(ushort h) {
    union { unsigned u; float f; } v; v.u = ((unsigned)h) << 16;
    return v.f;
}

#define STORE_HL(dh, dl, off, v) {                                              \
    ushort h0=f2bf((v).x),h1=f2bf((v).y),h2=f2bf((v).z),h3=f2bf((v).w);         \
    ushort l0=f2bf((v).x-bf2f(h0)),l1=f2bf((v).y-bf2f(h1)),                     \
           l2=f2bf((v).z-bf2f(h2)),l3=f2bf((v).w-bf2f(h3));                     \
    ushort4 hv; hv.x=h0;hv.y=h1;hv.z=h2;hv.w=h3;                                \
    ushort4 lv; lv.x=l0;lv.y=l1;lv.z=l2;lv.w=l3;                                \
    *(ushort4*)((dh)+(off))=hv; *(ushort4*)((dl)+(off))=lv; }

// one thread per edge: int atomics only (deg rank + cnt1)
__global__ void k_count(const int* __restrict__ ei, const int* __restrict__ x,
                        int* __restrict__ deg, int* __restrict__ cnt1,
                        int* __restrict__ epos) {
    int e = blockIdx.x * 256 + threadIdx.x;
    if (e >= E) return;
    int s = ei[e];
    epos[e] = atomicAdd(&deg[s], 1);
    int d = ei[E + e];
    int xv = x[d];
    if (xv) atomicAdd(&cnt1[s], xv);
}

// single block, 1024 threads, 20 elems/thread, int4-coalesced
__global__ void k_scan(const int* __restrict__ deg, int* __restrict__ rowptr) {
    __shared__ int wsum[16];
    const int tid = threadIdx.x, lane = tid & 63, w = tid >> 6;
    const int i0 = tid * 20;
    int loc[20];
    const int4* dv = (const int4*)(deg + i0);
    #pragma unroll
    for (int jj = 0; jj < 5; ++jj) {
        int4 v = dv[jj];
        int b = jj * 4;
        loc[b + 0] = (i0 + b + 0 < N) ? v.x : 0;
        loc[b + 1] = (i0 + b + 1 < N) ? v.y : 0;
        loc[b + 2] = (i0 + b + 2 < N) ? v.z : 0;
        loc[b + 3] = (i0 + b + 3 < N) ? v.w : 0;
    }
    int s = 0;
    #pragma unroll
    for (int j = 0; j < 20; ++j) s += loc[j];
    int t = s;
    #pragma unroll
    for (int off = 1; off < 64; off <<= 1) {
        int u = __shfl_up(t, off);
        if (lane >= off) t += u;
    }
    if (lane == 63) wsum[w] = t;
    __syncthreads();
    if (w == 0 && lane < 16) {
        int u = wsum[lane];
        #pragma unroll
        for (int off = 1; off < 16; off <<= 1) {
            int z = __shfl_up(u, off);
            if (lane >= off) u += z;
        }
        wsum[lane] = u;
    }
    __syncthreads();
    int excl = ((w == 0) ? 0 : wsum[w - 1]) + t - s;
    int o[20];
    #pragma unroll
    for (int j = 0; j < 20; ++j) { o[j] = excl; excl += loc[j]; }
    int4* rv = (int4*)(rowptr + i0);
    #pragma unroll
    for (int jj = 0; jj < 5; ++jj) {
        int b = jj * 4;
        if (i0 + b <= N)
            rv[jj] = make_int4(o[b + 0], o[b + 1], o[b + 2], o[b + 3]);
    }
}

// atomic-free fill: pk2[p] = (dst, eid)
__global__ void k_fill(const int* __restrict__ ei, const int* __restrict__ rowptr,
                       const int* __restrict__ epos, int2* __restrict__ pk2) {
    int e = blockIdx.x * 256 + threadIdx.x;
    if (e >= E) return;
    int s = ei[e], d = ei[E + e];
    pk2[rowptr[s] + epos[e]] = make_int2(d, e);
}

// 16 lanes per node, q<9 active: attr[n][q] = sum over CSR run of eattr[eid][q]
__global__ void k_attr(const float* __restrict__ eattr, const int* __restrict__ rowptr,
                       const int2* __restrict__ pk2, float* __restrict__ attr) {
    int t = blockIdx.x * 256 + threadIdx.x;
    int n = t >> 4, q = t & 15;
    if (n >= N || q >= EA) return;
    int p = rowptr[n], p1 = rowptr[n + 1];
    float s = 0.f;
    for (; p + 4 <= p1; p += 4) {
        int e0 = pk2[p].y, e1 = pk2[p + 1].y, e2 = pk2[p + 2].y, e3 = pk2[p + 3].y;
        float v0 = eattr[e0 * EA + q];
        float v1 = eattr[e1 * EA + q];
        float v2 = eattr[e2 * EA + q];
        float v3 = eattr[e3 * EA + q];
        s += v0; s += v1; s += v2; s += v3;
    }
    for (; p < p1; ++p) s += eattr[pk2[p].y * EA + q];
    attr[n * EA + q] = s;
}

// W1[l][k][n] -> w1c[l][n][k] bf16 hi/lo (k-contiguous for MFMA B-frags); same W2
__global__ void k_wprep(const float* __restrict__ W1, const float* __restrict__ W2,
                        ushort* __restrict__ w1hi, ushort* __restrict__ w1lo,
                        ushort* __restrict__ w2hi, ushort* __restrict__ w2lo) {
    int t = blockIdx.x * 256 + threadIdx.x;
    if (t < 3 * 128 * 128) {
        int l = t / 16384, r = t % 16384;
        int n = r >> 7, k = r & 127;
        float v = W1[l * 16384 + k * 128 + n];
        ushort h = f2bf(v);
        w1hi[t] = h;
        w1lo[t] = f2bf(v - bf2f(h));
    } else if (t < 3 * 128 * 128 + 3 * 128 * 64) {
        int t2 = t - 3 * 128 * 128;
        int l = t2 / 8192, r = t2 % 8192;
        int n = r >> 7, k = r & 127;
        float v = W2[l * 8192 + k * 64 + n];
        ushort h = f2bf(v);
        w2hi[t2] = h;
        w2lo[t2] = f2bf(v - bf2f(h));
    }
}

// one wave per node: acc = self + sum neighbor rows (bf16 in, f32 acc/out)
__global__ __launch_bounds__(256, 8) void k_gather(
        const ushort* __restrict__ h_in, float* __restrict__ aggF,
        const int* __restrict__ rowptr, const int2* __restrict__ pk2) {
    const int lane = threadIdx.x & 63;
    const int n = blockIdx.x * 4 + (threadIdx.x >> 6);
    const int p0 = rowptr[n], p1 = rowptr[n + 1];
    float acc = bf2f(h_in[n * H + lane]);
    int p = p0;
    for (; p + 8 <= p1; p += 8) {
        const int4* pv = (const int4*)(pk2 + p);
        int4 a = pv[0], b = pv[1], c = pv[2], d = pv[3];
        float v0 = bf2f(h_in[a.x * H + lane]);
        float v1 = bf2f(h_in[a.z * H + lane]);
        float v2 = bf2f(h_in[b.x * H + lane]);
        float v3 = bf2f(h_in[b.z * H + lane]);
        float v4 = bf2f(h_in[c.x * H + lane]);
        float v5 = bf2f(h_in[c.z * H + lane]);
        float v6 = bf2f(h_in[d.x * H + lane]);
        float v7 = bf2f(h_in[d.z * H + lane]);
        acc += v0; acc += v1; acc += v2; acc += v3;
        acc += v4; acc += v5; acc += v6; acc += v7;
    }
    for (; p < p1; ++p) acc += bf2f(h_in[pk2[p].x * H + lane]);
    aggF[n * H + lane] = acc;
}

// MFMA MLP: 64 rows/block, 4 waves. V (hi/lo bf16) in LDS, W from precomputed
// global bf16 hi/lo (k-contig). z1 BN+relu -> LDS hi/lo -> z2 -> global.
__global__ __launch_bounds__(256, 2) void k_mlp(
        const float* __restrict__ aggF, void* __restrict__ h_out,
        const int* __restrict__ rowptr, const float* __restrict__ attr,
        const int* __restrict__ cnt1, const int* __restrict__ xarr,
        const float* __restrict__ emb0,
        const float* __restrict__ WeL, const float* __restrict__ beL,
        const ushort* __restrict__ w1hi, const ushort* __restrict__ w1lo,
        const ushort* __restrict__ w2hi, const ushort* __restrict__ w2lo,
        const float* __restrict__ b1L, const float* __restrict__ gammaL,
        const float* __restrict__ betaL, const float* __restrict__ meanL,
        const float* __restrict__ varL, const float* __restrict__ b2L,
        const int* __restrict__ slip, const int* __restrict__ sltp,
        int mode, int relu_out, int store_bf16) {
    __shared__ ushort sm[4 * 64 * SVB];   // 69632 B -> 2 blocks/CU
    ushort* sVhi = sm;
    ushort* sVlo = sm + 64 * SVB;
    ushort* sZhi = sm + 2 * 64 * SVB;
    ushort* sZlo = sm + 3 * 64 * SVB;
    const int tid = threadIdx.x;
    const int n0 = blockIdx.x * 64;

    // ---- Phase A: build V (64 x 128) hi/lo in LDS ----
    {
        const int r = tid >> 2, u = tid & 3;    // 4 threads/row, 32 cols each
        const int n = n0 + r;
        const bool valid = n < N;
        ushort* dh = sVhi + r * SVB;
        ushort* dl = sVlo + r * SVB;
        if (u < 2) {
            const int c0 = u * 32;
            if (mode == 0) {
                float f0 = 0.f, f1 = 0.f;
                if (valid) {
                    int xv = xarr[n];
                    int degv = rowptr[n + 1] - rowptr[n];
                    int c1 = cnt1[n] + xv;
                    f1 = (float)c1;
                    f0 = (float)(degv + 1 - c1);
                }
                #pragma unroll
                for (int i = 0; i < 8; ++i) {
                    float4 e0 = *(const float4*)(emb0 + c0 + i * 4);
                    float4 e1 = *(const float4*)(emb0 + 64 + c0 + i * 4);
                    float4 v;
                    v.x = f0 * e0.x + f1 * e1.x;
                    v.y = f0 * e0.y + f1 * e1.y;
                    v.z = f0 * e0.z + f1 * e1.z;
                    v.w = f0 * e0.w + f1 * e1.w;
                    STORE_HL(dh, dl, c0 + i * 4, v);
                }
            } else {
                #pragma unroll
                for (int i = 0; i < 8; ++i) {
                    float4 v = make_float4(0.f, 0.f, 0.f, 0.f);
                    if (valid) v = *(const float4*)(aggF + n * H + c0 + i * 4);
                    STORE_HL(dh, dl, c0 + i * 4, v);
                }
            }
        } else {
            const int cc0 = (u - 2) * 32;
            float at[EA];
            float dcnt = 0.f, slt = 0.f;
            int sli = 0;
            if (valid) {
                sli = slip[0];
                slt = (float)sltp[0];
                dcnt = (float)(rowptr[n + 1] - rowptr[n] + 1);
                #pragma unroll
                for (int j = 0; j < EA; ++j) at[j] = attr[n * EA + j];
            } else {
                #pragma unroll
                for (int j = 0; j < EA; ++j) at[j] = 0.f;
            }
            #pragma unroll
            for (int i = 0; i < 8; ++i) {
                const int cc = cc0 + i * 4;
                float4 v = make_float4(0.f, 0.f, 0.f, 0.f);
                if (valid) {
                    float4 bv = *(const float4*)(beL + cc);
                    float4 sv = *(const float4*)(WeL + sli * H + cc);
                    v.x = slt * sv.x + dcnt * bv.x;
                    v.y = slt * sv.y + dcnt * bv.y;
                    v.z = slt * sv.z + dcnt * bv.z;
                    v.w = slt * sv.w + dcnt * bv.w;
                    #pragma unroll
                    for (int j = 0; j < EA; ++j) {
                        float4 wv = *(const float4*)(WeL + j * H + cc);
                        v.x += at[j] * wv.x; v.y += at[j] * wv.y;
                        v.z += at[j] * wv.z; v.w += at[j] * wv.w;
                    }
                }
                STORE_HL(dh, dl, 64 + cc, v);
            }
        }
    }
    __syncthreads();

    const int w = tid >> 6, lane = tid & 63;
    const int mr = lane & 15, quad = lane >> 4;

    // ---- Phase B: z1 = V @ W1 (hi/lo bf16 MFMA, 3-term) ----
    {
        const ushort* aH = sVhi + (w * 16 + mr) * SVB;
        const ushort* aL = sVlo + (w * 16 + mr) * SVB;
        f32x4 acc[8];
        #pragma unroll
        for (int t = 0; t < 8; ++t) acc[t] = (f32x4){0.f, 0.f, 0.f, 0.f};
        #pragma unroll
        for (int ks = 0; ks < 4; ++ks) {
            const int k0 = ks * 32 + quad * 8;
            s16x8 ahi = *(const s16x8*)(aH + k0);
            s16x8 alo = *(const s16x8*)(aL + k0);
            #pragma unroll
            for (int t = 0; t < 8; ++t) {
                const int nc = t * 16 + mr;
                s16x8 bhi = *(const s16x8*)(w1hi + nc * 128 + k0);
                s16x8 blo = *(const s16x8*)(w1lo + nc * 128 + k0);
                acc[t] = __builtin_amdgcn_mfma_f32_16x16x32_bf16(ahi, bhi, acc[t], 0, 0, 0);
                acc[t] = __builtin_amdgcn_mfma_f32_16x16x32_bf16(ahi, blo, acc[t], 0, 0, 0);
                acc[t] = __builtin_amdgcn_mfma_f32_16x16x32_bf16(alo, bhi, acc[t], 0, 0, 0);
            }
        }
        // BN (fold b1) + ReLU -> sZ hi/lo
        #pragma unroll
        for (int t = 0; t < 8; ++t) {
            const int c = t * 16 + mr;
            float sc = gammaL[c] * rsqrtf(varL[c] + EPS);
            float sh = (b1L[c] - meanL[c]) * sc + betaL[c];
            #pragma unroll
            for (int reg = 0; reg < 4; ++reg) {
                float z = fmaxf(acc[t][reg] * sc + sh, 0.f);
                int m = w * 16 + quad * 4 + reg;
                ushort hh = f2bf(z);
                sZhi[m * SVB + c] = hh;
                sZlo[m * SVB + c] = f2bf(z - bf2f(hh));
            }
        }
    }
    __syncthreads();

    // ---- Phase C: z2 = z1r @ W2 (+b2, +relu) ----
    {
        const ushort* zH = sZhi + (w * 16 + mr) * SVB;
        const ushort* zL = sZlo + (w * 16 + mr) * SVB;
        f32x4 acc2[4];
        #pragma unroll
        for (int t = 0; t < 4; ++t) acc2[t] = (f32x4){0.f, 0.f, 0.f, 0.f};
        #pragma unroll
        for (int ks = 0; ks < 4; ++ks) {
            const int k0 = ks * 32 + quad * 8;
            s16x8 ahi = *(const s16x8*)(zH + k0);
            s16x8 alo = *(const s16x8*)(zL + k0);
            #pragma unroll
            for (int t = 0; t < 4; ++t) {
                const int nc = t * 16 + mr;
                s16x8 bhi = *(const s16x8*)(w2hi + nc * 128 + k0);
                s16x8 blo = *(const s16x8*)(w2lo + nc * 128 + k0);
                acc2[t] = __builtin_amdgcn_mfma_f32_16x16x32_bf16(ahi, bhi, acc2[t], 0, 0, 0);
                acc2[t] = __builtin_amdgcn_mfma_f32_16x16x32_bf16(ahi, blo, acc2[t], 0, 0, 0);
                acc2[t] = __builtin_amdgcn_mfma_f32_16x16x32_bf16(alo, bhi, acc2[t], 0, 0, 0);
            }
        }
        #pragma unroll
        for (int t = 0; t < 4; ++t) {
            const int c = t * 16 + mr;
            float bb = b2L[c];
            #pragma unroll
            for (int reg = 0; reg < 4; ++reg) {
                int m = w * 16 + quad * 4 + reg;
                int n = n0 + m;
                if (n < N) {
                    float o = acc2[t][reg] + bb;
                    if (relu_out) o = fmaxf(o, 0.f);
                    if (store_bf16) ((ushort*)h_out)[n * H + c] = f2bf(o);
                    else            ((float*)h_out)[n * H + c] = o;
                }
            }
        }
    }
}

extern "C" void kernel_launch(void* const* d_in, const int* in_sizes, int n_in,
                              void* d_out, int out_size, void* d_ws, size_t ws_size,
                              hipStream_t stream) {
    const int*   x     = (const int*)d_in[0];
    const int*   ei    = (const int*)d_in[1];
    const float* eattr = (const float*)d_in[2];
    const float* emb0  = (const float*)d_in[3];
    const float* We    = (const float*)d_in[4];
    const float* be    = (const float*)d_in[5];
    const float* W1    = (const float*)d_in[6];
    const float* b1    = (const float*)d_in[7];
    const float* gamma = (const float*)d_in[8];
    const float* beta  = (const float*)d_in[9];
    const float* bnm   = (const float*)d_in[10];
    const float* bnv   = (const float*)d_in[11];
    const float* W2    = (const float*)d_in[12];
    const float* b2    = (const float*)d_in[13];
    const int*   slip  = (const int*)d_in[14];
    const int*   sltp  = (const int*)d_in[15];
    float* out = (float*)d_out;

    int*    deg    = (int*)d_ws + OFF_DEG;
    int*    cnt1   = (int*)d_ws + OFF_CNT1;
    float*  attr   = (float*)d_ws + OFF_ATTR;
    int*    rowptr = (int*)d_ws + OFF_ROWPTR;
    int*    epos   = (int*)d_ws + OFF_EPOS;
    int2*   pk2    = (int2*)((int*)d_ws + OFF_PK2);
    ushort* hb     = (ushort*)((int*)d_ws + OFF_HB);
    float*  aggF   = (float*)d_ws + OFF_AGG;
    ushort* w1hi   = (ushort*)((int*)d_ws + OFF_W1CHI);
    ushort* w1lo   = (ushort*)((int*)d_ws + OFF_W1CLO);
    ushort* w2hi   = (ushort*)((int*)d_ws + OFF_W2CHI);
    ushort* w2lo   = (ushort*)((int*)d_ws + OFF_W2CLO);

    hipMemsetAsync(d_ws, 0, (size_t)(2 * N) * 4, stream);

    k_count<<<dim3((E + 255) / 256), dim3(256), 0, stream>>>(ei, x, deg, cnt1, epos);
    k_wprep<<<dim3((3 * 128 * 128 + 3 * 128 * 64 + 255) / 256), dim3(256), 0, stream>>>(
        W1, W2, w1hi, w1lo, w2hi, w2lo);
    k_scan<<<dim3(1), dim3(1024), 0, stream>>>(deg, rowptr);
    k_fill<<<dim3((E + 255) / 256), dim3(256), 0, stream>>>(ei, rowptr, epos, pk2);
    k_attr<<<dim3((N * 16 + 255) / 256), dim3(256), 0, stream>>>(eattr, rowptr, pk2, attr);

    const int gblk = N / 4;          // 5000
    const int mblk = (N + 63) / 64;  // 313

    // layer 0: counts -> hb (bf16)
    k_mlp<<<dim3(mblk), dim3(256), 0, stream>>>(aggF, hb, rowptr, attr, cnt1, x, emb0,
        We + 0 * EA * H, be + 0 * H,
        w1hi + 0 * 16384, w1lo + 0 * 16384, w2hi + 0 * 8192, w2lo + 0 * 8192,
        b1 + 0 * 128, gamma + 0 * 128, beta + 0 * 128, bnm + 0 * 128, bnv + 0 * 128,
        b2 + 0 * 64, slip, sltp, 0, 1, 1);
    // layer 1: hb -> aggF -> hb
    k_gather<<<dim3(gblk), dim3(256), 0, stream>>>(hb, aggF, rowptr, pk2);
    k_mlp<<<dim3(mblk), dim3(256), 0, stream>>>(aggF, hb, rowptr, attr, cnt1, x, emb0,
        We + 1 * EA * H, be + 1 * H,
        w1hi + 1 * 16384, w1lo + 1 * 16384, w2hi + 1 * 8192, w2lo + 1 * 8192,
        b1 + 1 * 128, gamma + 1 * 128, beta + 1 * 128, bnm + 1 * 128, bnv + 1 * 128,
        b2 + 1 * 64, slip, sltp, 1, 1, 1);
    // layer 2: hb -> aggF -> out (f32, no final relu)
    k_gather<<<dim3(gblk), dim3(256), 0, stream>>>(hb, aggF, rowptr, pk2);
    k_mlp<<<dim3(mblk), dim3(256), 0, stream>>>(aggF, out, rowptr, attr, cnt1, x, emb0,
        We + 2 * EA * H, be + 2 * H,
        w1hi + 2 * 16384, w1lo + 2 * 16384, w2hi + 2 * 8192, w2lo + 2 * 8192,
        b1 + 2 * 128, gamma + 2 * 128, beta + 2 * 128, bnm + 2 * 128, bnv + 2 * 128,
        b2 + 2 * 64, slip, sltp, 1, 0, 0);
}

// Round 6
// 233.217 us; speedup vs baseline: 1.2163x; 1.2163x over previous
//
#include <hip/hip_runtime.h>
#include <hip/hip_bf16.h>

#define N   20000
#define E   320000
#define H   64
#define EA  9
#define EPS 1e-5f

#define SXS 136   // LDS row stride (ushort) for X and Z tiles

typedef short s16x8 __attribute__((ext_vector_type(8)));
typedef float f32x4 __attribute__((ext_vector_type(4)));

// ws offsets (u32 units); all 16B-aligned (divisible by 4)
#define OFF_DEG    0
#define OFF_CNT1   20000
#define OFF_ATTR   40000       // N*EA
#define OFF_ROWPTR 220000      // N+1 (+pad)
#define OFF_EPOS   240016      // E
#define OFF_PK2    560016      // E int2
#define OFF_HB     1200016     // N*H bf16
#define OFF_AGG    1840016     // N*H f32
#define OFF_W0HI   3120016     // 128*32 ushort = 2048 u32
#define OFF_W0LO   3122064
#define OFF_WBHI   3124112     // 2*128*96 ushort = 12288 u32
#define OFF_WBLO   3136400
#define OFF_W2HI   3148688     // 3*64*128 ushort = 12288 u32
#define OFF_W2LO   3160976
// end 3173264 u32 = 12.69 MB

static __device__ __forceinline__ ushort f2bf(float f) {
    union { float f; unsigned u; } v; v.f = f;
    unsigned r = (v.u + 0x7fffu + ((v.u >> 16) & 1u)) >> 16;
    return (ushort)r;
}
static __device__ __forceinline__ float bf2f(ushort h) {
    union { unsigned u; float f; } v; v.u = ((unsigned)h) << 16;
    return v.f;
}

#define STORE_HL(dh, dl, off, v) {                                              \
    ushort h0=f2bf((v).x),h1=f2bf((v).y),h2=f2bf((v).z),h3=f2bf((v).w);         \
    ushort l0=f2bf((v).x-bf2f(h0)),l1=f2bf((v).y-bf2f(h1)),                     \
           l2=f2bf((v).z-bf2f(h2)),l3=f2bf((v).w-bf2f(h3));                     \
    ushort4 hv; hv.x=h0;hv.y=h1;hv.z=h2;hv.w=h3;                                \
    ushort4 lv; lv.x=l0;lv.y=l1;lv.z=l2;lv.w=l3;                                \
    *(ushort4*)((dh)+(off))=hv; *(ushort4*)((dl)+(off))=lv; }

// one thread per edge: int atomics only (deg rank + cnt1)
__global__ void k_count(const int* __restrict__ ei, const int* __restrict__ x,
                        int* __restrict__ deg, int* __restrict__ cnt1,
                        int* __restrict__ epos) {
    int e = blockIdx.x * 256 + threadIdx.x;
    if (e >= E) return;
    int s = ei[e];
    epos[e] = atomicAdd(&deg[s], 1);
    int d = ei[E + e];
    int xv = x[d];
    if (xv) atomicAdd(&cnt1[s], xv);
}

// single block, 1024 threads, 20 elems/thread, int4-coalesced
__global__ void k_scan(const int* __restrict__ deg, int* __restrict__ rowptr) {
    __shared__ int wsum[16];
    const int tid = threadIdx.x, lane = tid & 63, w = tid >> 6;
    const int i0 = tid * 20;
    int loc[20];
    const int4* dv = (const int4*)(deg + i0);
    #pragma unroll
    for (int jj = 0; jj < 5; ++jj) {
        int4 v = dv[jj];
        int b = jj * 4;
        loc[b + 0] = (i0 + b + 0 < N) ? v.x : 0;
        loc[b + 1] = (i0 + b + 1 < N) ? v.y : 0;
        loc[b + 2] = (i0 + b + 2 < N) ? v.z : 0;
        loc[b + 3] = (i0 + b + 3 < N) ? v.w : 0;
    }
    int s = 0;
    #pragma unroll
    for (int j = 0; j < 20; ++j) s += loc[j];
    int t = s;
    #pragma unroll
    for (int off = 1; off < 64; off <<= 1) {
        int u = __shfl_up(t, off);
        if (lane >= off) t += u;
    }
    if (lane == 63) wsum[w] = t;
    __syncthreads();
    if (w == 0 && lane < 16) {
        int u = wsum[lane];
        #pragma unroll
        for (int off = 1; off < 16; off <<= 1) {
            int z = __shfl_up(u, off);
            if (lane >= off) u += z;
        }
        wsum[lane] = u;
    }
    __syncthreads();
    int excl = ((w == 0) ? 0 : wsum[w - 1]) + t - s;
    int o[20];
    #pragma unroll
    for (int j = 0; j < 20; ++j) { o[j] = excl; excl += loc[j]; }
    int4* rv = (int4*)(rowptr + i0);
    #pragma unroll
    for (int jj = 0; jj < 5; ++jj) {
        int b = jj * 4;
        if (i0 + b <= N)
            rv[jj] = make_int4(o[b + 0], o[b + 1], o[b + 2], o[b + 3]);
    }
}

// atomic-free fill: pk2[p] = (dst, eid)
__global__ void k_fill(const int* __restrict__ ei, const int* __restrict__ rowptr,
                       const int* __restrict__ epos, int2* __restrict__ pk2) {
    int e = blockIdx.x * 256 + threadIdx.x;
    if (e >= E) return;
    int s = ei[e], d = ei[E + e];
    pk2[rowptr[s] + epos[e]] = make_int2(d, e);
}

// 16 lanes per node, q<9 active: attr[n][q] = sum over CSR run of eattr[eid][q]
__global__ void k_attr(const float* __restrict__ eattr, const int* __restrict__ rowptr,
                       const int2* __restrict__ pk2, float* __restrict__ attr) {
    int t = blockIdx.x * 256 + threadIdx.x;
    int n = t >> 4, q = t & 15;
    if (n >= N || q >= EA) return;
    int p = rowptr[n], p1 = rowptr[n + 1];
    float s = 0.f;
    for (; p + 4 <= p1; p += 4) {
        int e0 = pk2[p].y, e1 = pk2[p + 1].y, e2 = pk2[p + 2].y, e3 = pk2[p + 3].y;
        float v0 = eattr[e0 * EA + q];
        float v1 = eattr[e1 * EA + q];
        float v2 = eattr[e2 * EA + q];
        float v3 = eattr[e3 * EA + q];
        s += v0; s += v1; s += v2; s += v3;
    }
    for (; p < p1; ++p) s += eattr[pk2[p].y * EA + q];
    attr[n * EA + q] = s;
}

// Build folded weight tensors (bf16 hi/lo, [n][k] k-contiguous):
//  W0 (layer0, K=32): k0,1 = emb0@W1_top ; k2..10 = We@W1_bot ; k11 = be@W1_bot ;
//                     k12 = slt*We[sli]@W1_bot ; k13..31 = 0
//  WB (layers1,2, K=96): k<64 = W1_top ; k64..72 = We@W1_bot ; k73 = be@W1_bot ;
//                     k74 = slt*We[sli]@W1_bot ; k75..95 = 0
//  W2c (all layers, K=128): transpose of W2
__global__ void k_wprep(const float* __restrict__ W1, const float* __restrict__ W2,
                        const float* __restrict__ emb0, const float* __restrict__ We,
                        const float* __restrict__ be,
                        const int* __restrict__ slip, const int* __restrict__ sltp,
                        ushort* __restrict__ w0hi, ushort* __restrict__ w0lo,
                        ushort* __restrict__ wbhi, ushort* __restrict__ wblo,
                        ushort* __restrict__ w2hi, ushort* __restrict__ w2lo) {
    int t = blockIdx.x * 256 + threadIdx.x;
    if (t < 4096) {
        int n = t >> 5, k = t & 31;
        float v = 0.f;
        if (k < 2) {
            for (int m = 0; m < 64; ++m) v += emb0[k * 64 + m] * W1[m * 128 + n];
        } else if (k < 11) {
            int j = k - 2;
            for (int m = 0; m < 64; ++m) v += We[j * 64 + m] * W1[(64 + m) * 128 + n];
        } else if (k == 11) {
            for (int m = 0; m < 64; ++m) v += be[m] * W1[(64 + m) * 128 + n];
        } else if (k == 12) {
            float slt = (float)sltp[0]; int sli = slip[0];
            for (int m = 0; m < 64; ++m) v += We[sli * 64 + m] * W1[(64 + m) * 128 + n];
            v *= slt;
        }
        ushort h = f2bf(v);
        w0hi[t] = h; w0lo[t] = f2bf(v - bf2f(h));
    } else if (t < 4096 + 24576) {
        int t2 = t - 4096;
        int l = 1 + t2 / 12288, r = t2 % 12288;
        int n = r / 96, k = r % 96;
        const float* W1L = W1 + l * 16384;
        const float* WeL = We + l * EA * H;
        const float* beL = be + l * H;
        float v = 0.f;
        if (k < 64) {
            v = W1L[k * 128 + n];
        } else if (k < 73) {
            int j = k - 64;
            for (int m = 0; m < 64; ++m) v += WeL[j * 64 + m] * W1L[(64 + m) * 128 + n];
        } else if (k == 73) {
            for (int m = 0; m < 64; ++m) v += beL[m] * W1L[(64 + m) * 128 + n];
        } else if (k == 74) {
            float slt = (float)sltp[0]; int sli = slip[0];
            for (int m = 0; m < 64; ++m) v += WeL[sli * 64 + m] * W1L[(64 + m) * 128 + n];
            v *= slt;
        }
        ushort h = f2bf(v);
        wbhi[t2] = h; wblo[t2] = f2bf(v - bf2f(h));
    } else if (t < 4096 + 24576 + 24576) {
        int t2 = t - 4096 - 24576;
        int l = t2 / 8192, r = t2 % 8192;
        int n = r >> 7, k = r & 127;
        float v = W2[l * 8192 + k * 64 + n];
        ushort h = f2bf(v);
        w2hi[t2] = h; w2lo[t2] = f2bf(v - bf2f(h));
    }
}

// one wave per node: acc = self + sum neighbor rows (bf16 in, f32 acc/out)
__global__ __launch_bounds__(256, 8) void k_gather(
        const ushort* __restrict__ h_in, float* __restrict__ aggF,
        const int* __restrict__ rowptr, const int2* __restrict__ pk2) {
    const int lane = threadIdx.x & 63;
    const int n = blockIdx.x * 4 + (threadIdx.x >> 6);
    const int p0 = rowptr[n], p1 = rowptr[n + 1];
    float acc = bf2f(h_in[n * H + lane]);
    int p = p0;
    for (; p + 8 <= p1; p += 8) {
        const int4* pv = (const int4*)(pk2 + p);
        int4 a = pv[0], b = pv[1], c = pv[2], d = pv[3];
        float v0 = bf2f(h_in[a.x * H + lane]);
        float v1 = bf2f(h_in[a.z * H + lane]);
        float v2 = bf2f(h_in[b.x * H + lane]);
        float v3 = bf2f(h_in[b.z * H + lane]);
        float v4 = bf2f(h_in[c.x * H + lane]);
        float v5 = bf2f(h_in[c.z * H + lane]);
        float v6 = bf2f(h_in[d.x * H + lane]);
        float v7 = bf2f(h_in[d.z * H + lane]);
        acc += v0; acc += v1; acc += v2; acc += v3;
        acc += v4; acc += v5; acc += v6; acc += v7;
    }
    for (; p < p1; ++p) acc += bf2f(h_in[pk2[p].x * H + lane]);
    aggF[n * H + lane] = acc;
}

// Folded MFMA MLP: 64 rows/block, 4 waves, 34.8 KB LDS -> 4 blocks/CU.
// mode 1: X = [agg(64) | attr(9) | deg+1 | 1 | 0...], K=96 (nK=3)
// mode 0: X = [c0 c1 | attr(9) | deg+1 | 1 | 0...], K=32 (nK=1)
// z1 = X@WB (hi/lo 3-term), BN+ReLU -> Z (hi/lo, same LDS), z2 = Z@W2c.
__global__ __launch_bounds__(256, 4) void k_mlp(
        const float* __restrict__ aggF, void* __restrict__ h_out,
        const int* __restrict__ rowptr, const float* __restrict__ attr,
        const int* __restrict__ cnt1, const int* __restrict__ xarr,
        const ushort* __restrict__ wBhi, const ushort* __restrict__ wBlo,
        const ushort* __restrict__ w2hi, const ushort* __restrict__ w2lo,
        const float* __restrict__ b1L, const float* __restrict__ gammaL,
        const float* __restrict__ betaL, const float* __restrict__ meanL,
        const float* __restrict__ varL, const float* __restrict__ b2L,
        int wkStride, int nK, int mode, int relu_out, int store_bf16) {
    __shared__ ushort sm[2 * 64 * SXS];   // 34816 B
    ushort* sHi = sm;
    ushort* sLo = sm + 64 * SXS;
    const int tid = threadIdx.x;
    const int n0 = blockIdx.x * 64;

    // ---- Phase A: build X hi/lo ----
    {
        const int r = tid >> 2, u = tid & 3;
        const int n = n0 + r;
        const bool valid = n < N;
        ushort* dh = sHi + r * SXS;
        ushort* dl = sLo + r * SXS;
        if (mode == 1) {
            #pragma unroll
            for (int i = 0; i < 4; ++i) {
                float4 v = make_float4(0.f, 0.f, 0.f, 0.f);
                if (valid) v = *(const float4*)(aggF + n * H + u * 16 + i * 4);
                STORE_HL(dh, dl, u * 16 + i * 4, v);
            }
            if (u == 0) {
                float c[16];
                #pragma unroll
                for (int j = 0; j < 16; ++j) c[j] = 0.f;
                if (valid) {
                    #pragma unroll
                    for (int j = 0; j < EA; ++j) c[j] = attr[n * EA + j];
                    c[9]  = (float)(rowptr[n + 1] - rowptr[n] + 1);
                    c[10] = 1.f;
                }
                #pragma unroll
                for (int i = 0; i < 4; ++i) {
                    float4 v = make_float4(c[i * 4], c[i * 4 + 1], c[i * 4 + 2], c[i * 4 + 3]);
                    STORE_HL(dh, dl, 64 + i * 4, v);
                }
            } else if (u == 1) {
                float4 z = make_float4(0.f, 0.f, 0.f, 0.f);
                #pragma unroll
                for (int i = 0; i < 4; ++i) STORE_HL(dh, dl, 80 + i * 4, z);
            }
        } else {
            if (u == 0) {
                float c[16];
                #pragma unroll
                for (int j = 0; j < 16; ++j) c[j] = 0.f;
                if (valid) {
                    int xv = xarr[n];
                    int degv = rowptr[n + 1] - rowptr[n];
                    int c1 = cnt1[n] + xv;
                    c[0] = (float)(degv + 1 - c1);
                    c[1] = (float)c1;
                    #pragma unroll
                    for (int j = 0; j < EA; ++j) c[2 + j] = attr[n * EA + j];
                    c[11] = (float)(degv + 1);
                    c[12] = 1.f;
                }
                #pragma unroll
                for (int i = 0; i < 4; ++i) {
                    float4 v = make_float4(c[i * 4], c[i * 4 + 1], c[i * 4 + 2], c[i * 4 + 3]);
                    STORE_HL(dh, dl, i * 4, v);
                }
            } else if (u == 1) {
                float4 z = make_float4(0.f, 0.f, 0.f, 0.f);
                #pragma unroll
                for (int i = 0; i < 4; ++i) STORE_HL(dh, dl, 16 + i * 4, z);
            }
        }
    }
    __syncthreads();

    const int w = tid >> 6, lane = tid & 63;
    const int mr = lane & 15, quad = lane >> 4;

    // ---- Phase B: z1 = X @ WB (hi/lo 3-term) ----
    f32x4 acc[8];
    {
        const ushort* aHp = sHi + (w * 16 + mr) * SXS;
        const ushort* aLp = sLo + (w * 16 + mr) * SXS;
        #pragma unroll
        for (int t = 0; t < 8; ++t) acc[t] = (f32x4){0.f, 0.f, 0.f, 0.f};
        for (int ks = 0; ks < nK; ++ks) {
            const int k0 = ks * 32 + quad * 8;
            s16x8 ahi = *(const s16x8*)(aHp + k0);
            s16x8 alo = *(const s16x8*)(aLp + k0);
            #pragma unroll
            for (int t = 0; t < 8; ++t) {
                const int nc = t * 16 + mr;
                s16x8 bhi = *(const s16x8*)(wBhi + nc * wkStride + k0);
                s16x8 blo = *(const s16x8*)(wBlo + nc * wkStride + k0);
                acc[t] = __builtin_amdgcn_mfma_f32_16x16x32_bf16(ahi, bhi, acc[t], 0, 0, 0);
                acc[t] = __builtin_amdgcn_mfma_f32_16x16x32_bf16(ahi, blo, acc[t], 0, 0, 0);
                acc[t] = __builtin_amdgcn_mfma_f32_16x16x32_bf16(alo, bhi, acc[t], 0, 0, 0);
            }
        }
    }
    __syncthreads();   // X fully consumed; reuse LDS for Z

    // ---- BN (fold b1) + ReLU -> Z hi/lo ----
    {
        #pragma unroll
        for (int t = 0; t < 8; ++t) {
            const int c = t * 16 + mr;
            float sc = gammaL[c] * rsqrtf(varL[c] + EPS);
            float sh = (b1L[c] - meanL[c]) * sc + betaL[c];
            #pragma unroll
            for (int reg = 0; reg < 4; ++reg) {
                float z = fmaxf(acc[t][reg] * sc + sh, 0.f);
                int m = w * 16 + quad * 4 + reg;
                ushort hh = f2bf(z);
                sHi[m * SXS + c] = hh;
                sLo[m * SXS + c] = f2bf(z - bf2f(hh));
            }
        }
    }
    __syncthreads();

    // ---- Phase C: z2 = Z @ W2c (+b2, +relu) ----
    {
        const ushort* zH = sHi + (w * 16 + mr) * SXS;
        const ushort* zL = sLo + (w * 16 + mr) * SXS;
        f32x4 acc2[4];
        #pragma unroll
        for (int t = 0; t < 4; ++t) acc2[t] = (f32x4){0.f, 0.f, 0.f, 0.f};
        #pragma unroll
        for (int ks = 0; ks < 4; ++ks) {
            const int k0 = ks * 32 + quad * 8;
            s16x8 ahi = *(const s16x8*)(zH + k0);
            s16x8 alo = *(const s16x8*)(zL + k0);
            #pragma unroll
            for (int t = 0; t < 4; ++t) {
                const int nc = t * 16 + mr;
                s16x8 bhi = *(const s16x8*)(w2hi + nc * 128 + k0);
                s16x8 blo = *(const s16x8*)(w2lo + nc * 128 + k0);
                acc2[t] = __builtin_amdgcn_mfma_f32_16x16x32_bf16(ahi, bhi, acc2[t], 0, 0, 0);
                acc2[t] = __builtin_amdgcn_mfma_f32_16x16x32_bf16(ahi, blo, acc2[t], 0, 0, 0);
                acc2[t] = __builtin_amdgcn_mfma_f32_16x16x32_bf16(alo, bhi, acc2[t], 0, 0, 0);
            }
        }
        #pragma unroll
        for (int t = 0; t < 4; ++t) {
            const int c = t * 16 + mr;
            float bb = b2L[c];
            #pragma unroll
            for (int reg = 0; reg < 4; ++reg) {
                int m = w * 16 + quad * 4 + reg;
                int n = n0 + m;
                if (n < N) {
                    float o = acc2[t][reg] + bb;
                    if (relu_out) o = fmaxf(o, 0.f);
                    if (store_bf16) ((ushort*)h_out)[n * H + c] = f2bf(o);
                    else            ((float*)h_out)[n * H + c] = o;
                }
            }
        }
    }
}

extern "C" void kernel_launch(void* const* d_in, const int* in_sizes, int n_in,
                              void* d_out, int out_size, void* d_ws, size_t ws_size,
                              hipStream_t stream) {
    const int*   x     = (const int*)d_in[0];
    const int*   ei    = (const int*)d_in[1];
    const float* eattr = (const float*)d_in[2];
    const float* emb0  = (const float*)d_in[3];
    const float* We    = (const float*)d_in[4];
    const float* be    = (const float*)d_in[5];
    const float* W1    = (const float*)d_in[6];
    const float* b1    = (const float*)d_in[7];
    const float* gamma = (const float*)d_in[8];
    const float* beta  = (const float*)d_in[9];
    const float* bnm   = (const float*)d_in[10];
    const float* bnv   = (const float*)d_in[11];
    const float* W2    = (const float*)d_in[12];
    const float* b2    = (const float*)d_in[13];
    const int*   slip  = (const int*)d_in[14];
    const int*   sltp  = (const int*)d_in[15];
    float* out = (float*)d_out;

    int*    deg    = (int*)d_ws + OFF_DEG;
    int*    cnt1   = (int*)d_ws + OFF_CNT1;
    float*  attr   = (float*)d_ws + OFF_ATTR;
    int*    rowptr = (int*)d_ws + OFF_ROWPTR;
    int*    epos   = (int*)d_ws + OFF_EPOS;
    int2*   pk2    = (int2*)((int*)d_ws + OFF_PK2);
    ushort* hb     = (ushort*)((int*)d_ws + OFF_HB);
    float*  aggF   = (float*)d_ws + OFF_AGG;
    ushort* w0hi   = (ushort*)((int*)d_ws + OFF_W0HI);
    ushort* w0lo   = (ushort*)((int*)d_ws + OFF_W0LO);
    ushort* wbhi   = (ushort*)((int*)d_ws + OFF_WBHI);
    ushort* wblo   = (ushort*)((int*)d_ws + OFF_WBLO);
    ushort* w2hi   = (ushort*)((int*)d_ws + OFF_W2HI);
    ushort* w2lo   = (ushort*)((int*)d_ws + OFF_W2LO);

    hipMemsetAsync(d_ws, 0, (size_t)(2 * N) * 4, stream);

    k_count<<<dim3((E + 255) / 256), dim3(256), 0, stream>>>(ei, x, deg, cnt1, epos);
    k_wprep<<<dim3(208), dim3(256), 0, stream>>>(W1, W2, emb0, We, be, slip, sltp,
                                                 w0hi, w0lo, wbhi, wblo, w2hi, w2lo);
    k_scan<<<dim3(1), dim3(1024), 0, stream>>>(deg, rowptr);
    k_fill<<<dim3((E + 255) / 256), dim3(256), 0, stream>>>(ei, rowptr, epos, pk2);
    k_attr<<<dim3((N * 16 + 255) / 256), dim3(256), 0, stream>>>(eattr, rowptr, pk2, attr);

    const int gblk = N / 4;          // 5000
    const int mblk = (N + 63) / 64;  // 313

    // layer 0: folded counts -> hb (bf16), K=32, 1 kstep
    k_mlp<<<dim3(mblk), dim3(256), 0, stream>>>(aggF, hb, rowptr, attr, cnt1, x,
        w0hi, w0lo, w2hi + 0 * 8192, w2lo + 0 * 8192,
        b1 + 0 * 128, gamma + 0 * 128, beta + 0 * 128, bnm + 0 * 128, bnv + 0 * 128,
        b2 + 0 * 64, 32, 1, 0, 1, 1);
    // layer 1: hb -> aggF -> hb, K=96, 3 ksteps
    k_gather<<<dim3(gblk), dim3(256), 0, stream>>>(hb, aggF, rowptr, pk2);
    k_mlp<<<dim3(mblk), dim3(256), 0, stream>>>(aggF, hb, rowptr, attr, cnt1, x,
        wbhi + 0 * 12288, wblo + 0 * 12288, w2hi + 1 * 8192, w2lo + 1 * 8192,
        b1 + 1 * 128, gamma + 1 * 128, beta + 1 * 128, bnm + 1 * 128, bnv + 1 * 128,
        b2 + 1 * 64, 96, 3, 1, 1, 1);
    // layer 2: hb -> aggF -> out (f32, no final relu)
    k_gather<<<dim3(gblk), dim3(256), 0, stream>>>(hb, aggF, rowptr, pk2);
    k_mlp<<<dim3(mblk), dim3(256), 0, stream>>>(aggF, out, rowptr, attr, cnt1, x,
        wbhi + 1 * 12288, wblo + 1 * 12288, w2hi + 2 * 8192, w2lo + 2 * 8192,
        b1 + 2 * 128, gamma + 2 * 128, beta + 2 * 128, bnm + 2 * 128, bnv + 2 * 128,
        b2 + 2 * 64, 96, 3, 1, 0, 0);
}